// Round 2
// 2069.410 us; speedup vs baseline: 4.2863x; 4.2863x over previous
//
#include <hip/hip_runtime.h>
#include <math.h>

// Problem constants
#define B_    2
#define C_    128
#define H_    512
#define W_    512
#define NWIN  4096      // 64*64 windows per batch
#define NWF   1228      // int(4096*0.3)
#define NSEL  (B_*NWF)  // 2456
#define SCALE 0.08838834764831845f  // 128^-0.5

#define WFS   132       // padded row stride for wf_s (breaks power-of-2 column strides)

__device__ __forceinline__ float wave_max64(float v){
  #pragma unroll
  for (int off = 32; off; off >>= 1) v = fmaxf(v, __shfl_xor(v, off, 64));
  return v;
}
__device__ __forceinline__ float wave_sum64(float v){
  #pragma unroll
  for (int off = 32; off; off >>= 1) v += __shfl_xor(v, off, 64);
  return v;
}
__device__ __forceinline__ float gelu_f(float x){
  return 0.5f * x * (1.0f + erff(x * 0.70710678118654752440f));
}

// ---------------- window scores: mean of uncertainty per 8x8 window ----------
__global__ void score_k(const float* __restrict__ unc, float* __restrict__ scores){
  int win = blockIdx.x;            // b*4096 + ih*64 + iw
  int b = win >> 12, w12 = win & 4095;
  int ih = w12 >> 6, iw = w12 & 63;
  int t = threadIdx.x, r = t >> 3, s = t & 7;
  float v = unc[((size_t)b*512 + ih*8 + r)*512 + iw*8 + s];
  v = wave_sum64(v);
  if (t == 0) scores[win] = v * (1.0f/64.0f);
}

// ---------------- top-k selection via exact rank (ties -> lower index) -------
__global__ void select_k(const float* __restrict__ scores, int* __restrict__ sel){
  int b = blockIdx.x;
  __shared__ float s[NWIN];
  for (int i = threadIdx.x; i < NWIN; i += 1024) s[i] = scores[b*NWIN + i];
  __syncthreads();
  for (int w = threadIdx.x; w < NWIN; w += 1024){
    float mys = s[w];
    int rank = 0;
    for (int j2 = 0; j2 < NWIN; ++j2){
      float o = s[j2];
      rank += (o > mys) || (o == mys && j2 < w);
    }
    if (rank < NWF) sel[b*NWF + rank] = w;
  }
}

// ---------------- 64x64-block pooling -> g[b][p][c]  (p = i*8+k) -------------
__global__ void pool_k(const float* __restrict__ fm, float* __restrict__ g){
  int id = blockIdx.x;             // (b*128 + c)*64 + p, 16384 blocks
  int p = id & 63, c = (id >> 6) & 127, b = id >> 13;
  int i = p >> 3, k = p & 7;
  const float* base = fm + (((size_t)b*128 + c)*512 + i*64)*512 + k*64;
  int tid = threadIdx.x;
  float sum = 0.0f;
  #pragma unroll
  for (int it = 0; it < 16; ++it){
    int f = it*256 + tid;
    int j2 = f >> 6, l = f & 63;
    sum += base[(size_t)j2*512 + l];
  }
  __shared__ float red[256];
  red[tid] = sum; __syncthreads();
  for (int s2 = 128; s2; s2 >>= 1){
    if (tid < s2) red[tid] += red[tid + s2];
    __syncthreads();
  }
  if (tid == 0) g[((b*64 + p) << 7) + c] = red[0] * (1.0f/4096.0f);
}

// ---------------- k,v = g @ kv_g_w.T  (v written packed over p-quads) --------
// vbp quad layout: quad index (b*16 + p/4)*128 + c holds {v[b,4q+0..3,c]}
__global__ void kv_k(const float* __restrict__ g, const float* __restrict__ kvw,
                     float* __restrict__ kbuf, float* __restrict__ vbp){
  int gid = blockIdx.x*256 + threadIdx.x;   // B*64*128 = 16384
  int c = gid & 127, p = (gid >> 7) & 63, b = gid >> 13;
  const float* grow = g + ((b*64 + p) << 7);
  const float* wk = kvw + (c << 7);
  const float* wv = kvw + ((128 + c) << 7);
  float ka = 0.0f, va = 0.0f;
  #pragma unroll 8
  for (int d = 0; d < 128; ++d){ float gv = grow[d]; ka += gv*wk[d]; va += gv*wv[d]; }
  kbuf[gid] = ka;
  vbp[((((b*16 + (p >> 2))*128 + c)) << 2) + (p & 3)] = va;
}

// ---------------- Mb = k_b @ q_g_w, written packed over d-quads --------------
// mbp quad layout: quad index (b*32 + d/4)*64 + p holds {Mb[b,p,4q+0..3]}
// NOTE: mbp aliases g's workspace slot; g is dead once kv_k completed and
// mb_k reads only kbuf (stream-ordered, no overlap).
__global__ void mb_k(const float* __restrict__ kbuf, const float* __restrict__ qgw,
                     float* __restrict__ mbp){
  int gid = blockIdx.x*256 + threadIdx.x;   // B*64*128
  int d = gid & 127, p = (gid >> 7) & 63, b = gid >> 13;
  const float* krow = kbuf + ((b*64 + p) << 7);
  float acc = 0.0f;
  #pragma unroll 8
  for (int c = 0; c < 128; ++c) acc += krow[c] * qgw[(c << 7) + d];
  mbp[((((b*32 + (d >> 2))*64 + p)) << 2) + (d & 3)] = acc;
}

// ---------------- M2 packed: quad (d/4)*128 + e = {M2T[e][4q+0..3]} ----------
// M2T[e][d] = sum_c Wq2[c][d] * Wk2[c][e]
__global__ void m2p_k(const float* __restrict__ qkvw, float* __restrict__ m2p){
  int gid = blockIdx.x*256 + threadIdx.x;   // 4096
  int e = gid & 127, dq = gid >> 7;
  float ax = 0.f, ay = 0.f, az = 0.f, aw = 0.f;
  for (int c = 0; c < 128; ++c){
    float kv2 = qkvw[((128 + c) << 7) + e];
    const float4 q4 = *(const float4*)(qkvw + (c << 7) + dq*4);
    ax += q4.x*kv2; ay += q4.y*kv2; az += q4.z*kv2; aw += q4.w*kv2;
  }
  ((float4*)m2p)[dq*128 + e] = make_float4(ax, ay, az, aw);
}

// ---------------- pack l0w / pw / Wv2 into [d/4][c] float4 layouts -----------
// NOTE: wv2p aliases kbuf's slot; kbuf is dead once mb_k completed (pack_k
// is launched after mb_k on the same stream).
__global__ void pack_k(const float* __restrict__ l0w, const float* __restrict__ pw,
                       const float* __restrict__ qkvw,
                       float* __restrict__ l0wp, float* __restrict__ pwp,
                       float* __restrict__ wv2p){
  int gid = blockIdx.x*256 + threadIdx.x;   // 4096
  int c = gid & 127, dq = gid >> 7;
  ((float4*)l0wp)[dq*128 + c] = *(const float4*)(l0w + (c << 7) + dq*4);
  ((float4*)pwp )[dq*128 + c] = *(const float4*)(pw  + (c << 7) + dq*4);
  ((float4*)wv2p)[dq*128 + c] = *(const float4*)(qkvw + ((256 + c) << 7) + dq*4);
}

// ---------------- megakernel: attn1 + MLP1 + attn2(+quirk) + MLP2 + scatter --
// wf_s: [64][132] padded, no swizzle (row quad-reads are uniform b128 broadcasts).
// aux_s: [64][128] linear (all accesses row-wise or lane-consecutive).
__global__ __launch_bounds__(256, 2) void mega_k(
    const float* __restrict__ fm, const int* __restrict__ sel,
    const float* __restrict__ mbp, const float* __restrict__ vbp,
    const float* __restrict__ m2p, const float* __restrict__ wv2p,
    const float* __restrict__ l0wp, const float* __restrict__ l0b,
    const float* __restrict__ pwp,  const float* __restrict__ pb,
    float* __restrict__ out)
{
  __shared__ float wf_s[64*WFS];   // 33 KB
  __shared__ float aux_s[64*128];  // 32 KB
  const int tid = threadIdx.x, lane = tid & 63, wv = tid >> 6;
  const int ci = tid & 127, hi = tid >> 7;   // GEMM phases: column ci, rows 2jj+hi
  const int j = blockIdx.x;                  // 0..2455
  const int b = j / NWF;
  const int win = sel[j];
  const int ih = win >> 6, iw = win & 63;

  // P1: gather window tokens  wf[t][c] = fm[b,c,ih*8+r,iw*8+s], t = r*8+s
  {
    const float* fmb = fm + ((size_t)b*128)*512*512;
    #pragma unroll
    for (int it = 0; it < 8; ++it){
      int idx = it*256 + tid;                 // f4 index over (c, r, q)
      int c = idx >> 4, rem = idx & 15, r = rem >> 1, q = rem & 1;
      float4 v = *(const float4*)(fmb + ((size_t)c*512 + ih*8 + r)*512 + iw*8 + q*4);
      int t0 = r*8 + q*4;
      wf_s[(t0+0)*WFS + c] = v.x;
      wf_s[(t0+1)*WFS + c] = v.y;
      wf_s[(t0+2)*WFS + c] = v.z;
      wf_s[(t0+3)*WFS + c] = v.w;
    }
  }
  __syncthreads();

  // P2a: attn1 scores + softmax.  lane = p.  rows t = wv*16 + rr.
  //      S1[t,p] = scale * sum_d wf[t,d]*Mb[b,p,d]; P -> aux[t][p]
  {
    const float4* mb4 = (const float4*)mbp + (size_t)b*2048 + lane;  // + dq*64
    float acc[16];
    #pragma unroll
    for (int r2 = 0; r2 < 16; ++r2) acc[r2] = 0.f;
    const float* wrow = wf_s + (wv*16)*WFS;
    float4 m = mb4[0];
    for (int dq = 0; dq < 32; ++dq){
      int nq = (dq + 1 < 32) ? dq + 1 : 31;
      float4 mn = mb4[nq*64];
      #pragma unroll
      for (int r2 = 0; r2 < 16; ++r2){
        float4 x = *(const float4*)(wrow + r2*WFS + dq*4);
        acc[r2] += x.x*m.x + x.y*m.y + x.z*m.z + x.w*m.w;
      }
      m = mn;
    }
    #pragma unroll
    for (int r2 = 0; r2 < 16; ++r2){
      float a = acc[r2] * SCALE;
      float mx = wave_max64(a);
      float e = __expf(a - mx);
      float p = e / wave_sum64(e);
      aux_s[(wv*16 + r2)*128 + lane] = p;
    }
  }
  __syncthreads();

  // P2b: wf += P @ v.  thread: column ci, rows 2jj+hi.
  {
    const float4* v4p = (const float4*)vbp + (size_t)b*2048 + ci;  // + pq*128
    float acc[32];
    #pragma unroll
    for (int jj = 0; jj < 32; ++jj) acc[jj] = 0.f;
    float4 v = v4p[0];
    for (int pq = 0; pq < 16; ++pq){
      int nq = (pq + 1 < 16) ? pq + 1 : 15;
      float4 vn = v4p[nq*128];
      #pragma unroll
      for (int jj = 0; jj < 32; ++jj){
        float4 p4 = *(const float4*)(aux_s + (2*jj + hi)*128 + pq*4);
        acc[jj] += p4.x*v.x + p4.y*v.y + p4.z*v.z + p4.w*v.w;
      }
      v = vn;
    }
    #pragma unroll
    for (int jj = 0; jj < 32; ++jj) wf_s[(2*jj + hi)*WFS + ci] += acc[jj];
  }
  __syncthreads();

  // P3: MLP1  wf += gelu(wf @ l0w^T + l0b)
  {
    const float4* w4 = (const float4*)l0wp + ci;
    float bias = l0b[ci];
    float acc[32];
    #pragma unroll
    for (int jj = 0; jj < 32; ++jj) acc[jj] = bias;
    float4 w = w4[0];
    for (int dq = 0; dq < 32; ++dq){
      int nq = (dq + 1 < 32) ? dq + 1 : 31;
      float4 wn = w4[nq*128];
      #pragma unroll
      for (int jj = 0; jj < 32; ++jj){
        float4 x = *(const float4*)(wf_s + (2*jj + hi)*WFS + dq*4);
        acc[jj] += x.x*w.x + x.y*w.y + x.z*w.z + x.w*w.w;
      }
      w = wn;
    }
    __syncthreads();   // all reads of wf done before in-place update
    #pragma unroll
    for (int jj = 0; jj < 32; ++jj)
      wf_s[(2*jj + hi)*WFS + ci] += gelu_f(acc[jj]);
  }
  __syncthreads();

  // P4: T = wf @ M2 -> aux   (T[t,e] = sum_d wf[t,d] * M2T[e][d]); e = ci
  {
    const float4* w4 = (const float4*)m2p + ci;
    float acc[32];
    #pragma unroll
    for (int jj = 0; jj < 32; ++jj) acc[jj] = 0.f;
    float4 w = w4[0];
    for (int dq = 0; dq < 32; ++dq){
      int nq = (dq + 1 < 32) ? dq + 1 : 31;
      float4 wn = w4[nq*128];
      #pragma unroll
      for (int jj = 0; jj < 32; ++jj){
        float4 x = *(const float4*)(wf_s + (2*jj + hi)*WFS + dq*4);
        acc[jj] += x.x*w.x + x.y*w.y + x.z*w.z + x.w*w.w;
      }
      w = wn;
    }
    #pragma unroll
    for (int jj = 0; jj < 32; ++jj) aux_s[(2*jj + hi)*128 + ci] = acc[jj];
  }
  __syncthreads();

  // P5a: attn2 scores + softmax.  lane = t'.  rows t = wv*16 + rr.
  //      S2[t,t'] = scale * sum_e T[t,e]*wf[t',e]; P overwrites aux[t][0..63]
  {
    float acc[16];
    #pragma unroll
    for (int r2 = 0; r2 < 16; ++r2) acc[r2] = 0.f;
    const float* trow = aux_s + (wv*16)*128;
    for (int eq = 0; eq < 32; ++eq){
      float4 wr = *(const float4*)(wf_s + lane*WFS + eq*4);   // per-lane row read
      #pragma unroll
      for (int r2 = 0; r2 < 16; ++r2){
        float4 t4 = *(const float4*)(trow + r2*128 + eq*4);
        acc[r2] += t4.x*wr.x + t4.y*wr.y + t4.z*wr.z + t4.w*wr.w;
      }
    }
    #pragma unroll
    for (int r2 = 0; r2 < 16; ++r2){
      float a = acc[r2] * SCALE;
      float mx = wave_max64(a);
      float e = __expf(a - mx);
      float p = e / wave_sum64(e);
      aux_s[(wv*16 + r2)*128 + lane] = p;   // own rows: wave's T reads already done
    }
  }
  __syncthreads();

  // P5b: U = P @ wf, buffered in regs, then written over aux
  {
    float acc[32];
    #pragma unroll
    for (int jj = 0; jj < 32; ++jj) acc[jj] = 0.f;
    for (int tq = 0; tq < 16; ++tq){
      float w0 = wf_s[(4*tq + 0)*WFS + ci];   // lane-consecutive row reads
      float w1 = wf_s[(4*tq + 1)*WFS + ci];
      float w2 = wf_s[(4*tq + 2)*WFS + ci];
      float w3 = wf_s[(4*tq + 3)*WFS + ci];
      #pragma unroll
      for (int jj = 0; jj < 32; ++jj){
        float4 p4 = *(const float4*)(aux_s + (2*jj + hi)*128 + tq*4);
        acc[jj] += p4.x*w0 + p4.y*w1 + p4.z*w2 + p4.w*w3;
      }
    }
    __syncthreads();   // all P reads complete before U overwrites aux
    #pragma unroll
    for (int jj = 0; jj < 32; ++jj) aux_s[(2*jj + hi)*128 + ci] = acc[jj];
  }
  __syncthreads();

  // P6: av2 = U @ Wv2^T with the reference's swapaxes reshape quirk:
  //     target of (q=2jj+hi, cp=ci) is wf[ci>>1][(ci&1)*64 + q]
  {
    const float4* w4 = (const float4*)wv2p + ci;
    float acc[32];
    #pragma unroll
    for (int jj = 0; jj < 32; ++jj) acc[jj] = 0.f;
    float4 w = w4[0];
    for (int dq = 0; dq < 32; ++dq){
      int nq = (dq + 1 < 32) ? dq + 1 : 31;
      float4 wn = w4[nq*128];
      #pragma unroll
      for (int jj = 0; jj < 32; ++jj){
        float4 u4 = *(const float4*)(aux_s + (2*jj + hi)*128 + dq*4);
        acc[jj] += u4.x*w.x + u4.y*w.y + u4.z*w.z + u4.w*w.w;
      }
      w = wn;
    }
    int row = ci >> 1, cbase = (ci & 1)*64 + hi;
    #pragma unroll
    for (int jj = 0; jj < 32; ++jj)
      wf_s[row*WFS + cbase + 2*jj] += acc[jj];   // bijective targets, no race
  }
  __syncthreads();

  // P7: MLP2  wf += gelu(wf @ pw^T + pb)
  {
    const float4* w4 = (const float4*)pwp + ci;
    float bias = pb[ci];
    float acc[32];
    #pragma unroll
    for (int jj = 0; jj < 32; ++jj) acc[jj] = bias;
    float4 w = w4[0];
    for (int dq = 0; dq < 32; ++dq){
      int nq = (dq + 1 < 32) ? dq + 1 : 31;
      float4 wn = w4[nq*128];
      #pragma unroll
      for (int jj = 0; jj < 32; ++jj){
        float4 x = *(const float4*)(wf_s + (2*jj + hi)*WFS + dq*4);
        acc[jj] += x.x*w.x + x.y*w.y + x.z*w.z + x.w*w.w;
      }
      w = wn;
    }
    __syncthreads();
    #pragma unroll
    for (int jj = 0; jj < 32; ++jj)
      wf_s[(2*jj + hi)*WFS + ci] += gelu_f(acc[jj]);
  }
  __syncthreads();

  // P8: scatter back into out (pass-through copy already done)
  {
    float* outb = out + ((size_t)b*128)*512*512;
    #pragma unroll
    for (int it = 0; it < 8; ++it){
      int idx = it*256 + tid;
      int c = idx >> 4, rem = idx & 15, r = rem >> 1, q = rem & 1;
      int t0 = r*8 + q*4;
      float4 v;
      v.x = wf_s[(t0+0)*WFS + c];
      v.y = wf_s[(t0+1)*WFS + c];
      v.z = wf_s[(t0+2)*WFS + c];
      v.w = wf_s[(t0+3)*WFS + c];
      *(float4*)(outb + ((size_t)c*512 + ih*8 + r)*512 + iw*8 + q*4) = v;
    }
  }
}

extern "C" void kernel_launch(void* const* d_in, const int* in_sizes, int n_in,
                              void* d_out, int out_size, void* d_ws, size_t ws_size,
                              hipStream_t stream) {
  const float* fm   = (const float*)d_in[0];
  const float* unc  = (const float*)d_in[1];
  const float* qgw  = (const float*)d_in[2];
  const float* kvw  = (const float*)d_in[3];
  const float* l0w  = (const float*)d_in[4];
  const float* l0b  = (const float*)d_in[5];
  const float* qkvw = (const float*)d_in[6];
  const float* pw   = (const float*)d_in[7];
  const float* pb   = (const float*)d_in[8];
  float* out = (float*)d_out;

  // Workspace layout with live-range aliasing (total 110592 floats = 432 KB):
  //   scores: live score_k..select_k
  //   g     : live pool_k..kv_k      -> slot reused by mbp (written by mb_k)
  //   kbuf  : live kv_k..mb_k        -> slot reused by wv2p (written by pack_k)
  float* ws     = (float*)d_ws;
  float* scores = ws;                      // 8192
  int*   sel    = (int*)(ws + 8192);       // 2456 (padded to 4096)
  float* g      = ws + 12288;              // 16384
  float* mbp    = ws + 12288;              // aliases g
  float* kbuf   = ws + 28672;              // 16384
  float* wv2p   = ws + 28672;              // aliases kbuf
  float* vbp    = ws + 45056;              // 16384 (packed p-quads)
  float* m2p    = ws + 61440;              // 16384 (packed d-quads)
  float* l0wp   = ws + 77824;              // 16384
  float* pwp    = ws + 94208;              // 16384  (end: 110592 floats = 432 KB)

  // pass-through copy: out = feature_map (selected windows overwritten later)
  hipMemcpyAsync(out, fm, (size_t)B_*C_*H_*W_*sizeof(float),
                 hipMemcpyDeviceToDevice, stream);

  score_k <<<B_*NWIN, 64, 0, stream>>>(unc, scores);
  select_k<<<B_, 1024, 0, stream>>>(scores, sel);
  pool_k  <<<B_*C_*64, 256, 0, stream>>>(fm, g);
  kv_k    <<<64, 256, 0, stream>>>(g, kvw, kbuf, vbp);
  mb_k    <<<64, 256, 0, stream>>>(kbuf, qgw, mbp);   // writes mbp (g's slot)
  m2p_k   <<<16, 256, 0, stream>>>(qkvw, m2p);
  pack_k  <<<16, 256, 0, stream>>>(l0w, pw, qkvw, l0wp, pwp, wv2p); // wv2p = kbuf's slot
  mega_k  <<<NSEL, 256, 0, stream>>>(fm, sel, mbp, vbp, m2p, wv2p,
                                     l0wp, l0b, pwp, pb, out);
}

// Round 3
// 1859.957 us; speedup vs baseline: 4.7690x; 1.1126x over previous
//
#include <hip/hip_runtime.h>
#include <math.h>

// Problem constants
#define B_    2
#define C_    128
#define H_    512
#define W_    512
#define NWIN  4096      // 64*64 windows per batch
#define NWF   1228      // int(4096*0.3)
#define NSEL  (B_*NWF)  // 2456
#define SCALE 0.08838834764831845f  // 128^-0.5

#define WFS   132       // padded row stride for wf_s (16B-aligned rows: 132*4=528)

__device__ __forceinline__ float wave_max64(float v){
  #pragma unroll
  for (int off = 32; off; off >>= 1) v = fmaxf(v, __shfl_xor(v, off, 64));
  return v;
}
__device__ __forceinline__ float wave_sum64(float v){
  #pragma unroll
  for (int off = 32; off; off >>= 1) v += __shfl_xor(v, off, 64);
  return v;
}
__device__ __forceinline__ float gelu_f(float x){
  return 0.5f * x * (1.0f + erff(x * 0.70710678118654752440f));
}

// ---------------- window scores: mean of uncertainty per 8x8 window ----------
__global__ void score_k(const float* __restrict__ unc, float* __restrict__ scores){
  int win = blockIdx.x;            // b*4096 + ih*64 + iw
  int b = win >> 12, w12 = win & 4095;
  int ih = w12 >> 6, iw = w12 & 63;
  int t = threadIdx.x, r = t >> 3, s = t & 7;
  float v = unc[((size_t)b*512 + ih*8 + r)*512 + iw*8 + s];
  v = wave_sum64(v);
  if (t == 0) scores[win] = v * (1.0f/64.0f);
}

// ---------------- top-k selection via exact rank (ties -> lower index) -------
__global__ void select_k(const float* __restrict__ scores, int* __restrict__ sel){
  int b = blockIdx.x;
  __shared__ float s[NWIN];
  for (int i = threadIdx.x; i < NWIN; i += 1024) s[i] = scores[b*NWIN + i];
  __syncthreads();
  for (int w = threadIdx.x; w < NWIN; w += 1024){
    float mys = s[w];
    int rank = 0;
    for (int j2 = 0; j2 < NWIN; ++j2){
      float o = s[j2];
      rank += (o > mys) || (o == mys && j2 < w);
    }
    if (rank < NWF) sel[b*NWF + rank] = w;
  }
}

// ---------------- 64x64-block pooling -> g[b][p][c], FUSED with out=fm copy --
__global__ void pool_k(const float* __restrict__ fm, float* __restrict__ g,
                       float* __restrict__ out){
  int id = blockIdx.x;             // (b*128 + c)*64 + p, 16384 blocks
  int p = id & 63, c = (id >> 6) & 127, b = id >> 13;
  int i = p >> 3, k = p & 7;
  size_t off = (((size_t)b*128 + c)*512 + i*64)*512 + k*64;
  const float* base = fm + off;
  float* ob = out + off;
  int tid = threadIdx.x;
  float sum = 0.0f;
  #pragma unroll
  for (int it = 0; it < 4; ++it){
    int idx = it*256 + tid;
    int j2 = idx >> 4, l = (idx & 15)*4;
    float4 v = *(const float4*)(base + (size_t)j2*512 + l);
    *(float4*)(ob + (size_t)j2*512 + l) = v;     // pass-through copy fused here
    sum += v.x + v.y + v.z + v.w;
  }
  __shared__ float red[256];
  red[tid] = sum; __syncthreads();
  for (int s2 = 128; s2; s2 >>= 1){
    if (tid < s2) red[tid] += red[tid + s2];
    __syncthreads();
  }
  if (tid == 0) g[((b*64 + p) << 7) + c] = red[0] * (1.0f/4096.0f);
}

// ---------------- k,v = g @ kv_g_w.T  (v written packed over p-quads) --------
// vbp quad layout: quad index (b*16 + p/4)*128 + c holds {v[b,4q+0..3,c]}
__global__ void kv_k(const float* __restrict__ g, const float* __restrict__ kvw,
                     float* __restrict__ kbuf, float* __restrict__ vbp){
  int gid = blockIdx.x*256 + threadIdx.x;   // B*64*128 = 16384
  int c = gid & 127, p = (gid >> 7) & 63, b = gid >> 13;
  const float* grow = g + ((b*64 + p) << 7);
  const float* wk = kvw + (c << 7);
  const float* wv = kvw + ((128 + c) << 7);
  float ka = 0.0f, va = 0.0f;
  #pragma unroll 8
  for (int d = 0; d < 128; ++d){ float gv = grow[d]; ka += gv*wk[d]; va += gv*wv[d]; }
  kbuf[gid] = ka;
  vbp[((((b*16 + (p >> 2))*128 + c)) << 2) + (p & 3)] = va;
}

// ---------------- Mb = k_b @ q_g_w, written packed over d-quads --------------
// mbp quad layout: quad index (b*32 + d/4)*64 + p holds {Mb[b,p,4q+0..3]}
// NOTE: mbp aliases g's workspace slot (g dead after kv_k; stream-ordered).
__global__ void mb_k(const float* __restrict__ kbuf, const float* __restrict__ qgw,
                     float* __restrict__ mbp){
  int gid = blockIdx.x*256 + threadIdx.x;   // B*64*128
  int d = gid & 127, p = (gid >> 7) & 63, b = gid >> 13;
  const float* krow = kbuf + ((b*64 + p) << 7);
  float acc = 0.0f;
  #pragma unroll 8
  for (int c = 0; c < 128; ++c) acc += krow[c] * qgw[(c << 7) + d];
  mbp[((((b*32 + (d >> 2))*64 + p)) << 2) + (d & 3)] = acc;
}

// ---------------- M2 packed: quad (d/4)*128 + e = {M2T[e][4q+0..3]} ----------
// M2T[e][d] = sum_c Wq2[c][d] * Wk2[c][e]
__global__ void m2p_k(const float* __restrict__ qkvw, float* __restrict__ m2p){
  int gid = blockIdx.x*256 + threadIdx.x;   // 4096
  int e = gid & 127, dq = gid >> 7;
  float ax = 0.f, ay = 0.f, az = 0.f, aw = 0.f;
  for (int c = 0; c < 128; ++c){
    float kv2 = qkvw[((128 + c) << 7) + e];
    const float4 q4 = *(const float4*)(qkvw + (c << 7) + dq*4);
    ax += q4.x*kv2; ay += q4.y*kv2; az += q4.z*kv2; aw += q4.w*kv2;
  }
  ((float4*)m2p)[dq*128 + e] = make_float4(ax, ay, az, aw);
}

// ---------------- pack l0w / pw / Wv2 into [d/4][c] float4 layouts -----------
// NOTE: wv2p aliases kbuf's slot (kbuf dead after mb_k; stream-ordered).
__global__ void pack_k(const float* __restrict__ l0w, const float* __restrict__ pw,
                       const float* __restrict__ qkvw,
                       float* __restrict__ l0wp, float* __restrict__ pwp,
                       float* __restrict__ wv2p){
  int gid = blockIdx.x*256 + threadIdx.x;   // 4096
  int c = gid & 127, dq = gid >> 7;
  ((float4*)l0wp)[dq*128 + c] = *(const float4*)(l0w + (c << 7) + dq*4);
  ((float4*)pwp )[dq*128 + c] = *(const float4*)(pw  + (c << 7) + dq*4);
  ((float4*)wv2p)[dq*128 + c] = *(const float4*)(qkvw + ((256 + c) << 7) + dq*4);
}

// ---------------- megakernel ------------------------------------------------
// Wave wv owns rows r0..r0+15 (r0 = wv*16). Thread owns cols {lane, lane+64}
// in GEMM phases. All GEMM x-reads from LDS are full-wave single-address
// broadcasts. Row-local phases chain without barriers (same-wave lockstep).
__global__ __launch_bounds__(256, 2) void mega_k(
    const float* __restrict__ fm, const int* __restrict__ sel,
    const float* __restrict__ mbp, const float* __restrict__ vbp,
    const float* __restrict__ m2p, const float* __restrict__ wv2p,
    const float* __restrict__ l0wp, const float* __restrict__ l0b,
    const float* __restrict__ pwp,  const float* __restrict__ pb,
    float* __restrict__ out)
{
  __shared__ float wf_s[64*WFS];   // 33 KB
  __shared__ float aux_s[64*128];  // 32 KB
  const int tid = threadIdx.x, lane = tid & 63, wv = tid >> 6;
  const int r0 = wv*16;
  const int j = blockIdx.x;                  // 0..2455
  const int b = j / NWF;
  const int win = sel[j];
  const int ih = win >> 6, iw = win & 63;

  // P1: gather window tokens  wf[t][c] = fm[b,c,ih*8+r,iw*8+s], t = r*8+s
  {
    const float* fmb = fm + ((size_t)b*128)*512*512;
    #pragma unroll
    for (int it = 0; it < 8; ++it){
      int idx = it*256 + tid;
      int c = idx >> 4, rem = idx & 15, r = rem >> 1, q = rem & 1;
      float4 v = *(const float4*)(fmb + ((size_t)c*512 + ih*8 + r)*512 + iw*8 + q*4);
      int t0 = r*8 + q*4;
      wf_s[(t0+0)*WFS + c] = v.x;
      wf_s[(t0+1)*WFS + c] = v.y;
      wf_s[(t0+2)*WFS + c] = v.z;
      wf_s[(t0+3)*WFS + c] = v.w;
    }
  }
  __syncthreads();

  // P2a: S1[t,p] = scale * sum_d wf[t,d]*Mb[b,p,d]; softmax over p -> aux[t][p]
  //      t = r0..r0+15 (own rows), p = lane.
  {
    const float4* mb4 = (const float4*)mbp + (size_t)b*2048 + lane;  // + dq*64
    float acc[16];
    #pragma unroll
    for (int k = 0; k < 16; ++k) acc[k] = 0.f;
    const float* wrow = wf_s + r0*WFS;
    float4 m = mb4[0];
    for (int dq = 0; dq < 32; ++dq){
      int nq = (dq + 1 < 32) ? dq + 1 : 31;
      float4 mn = mb4[nq*64];
      #pragma unroll
      for (int k = 0; k < 16; ++k){
        float4 x = *(const float4*)(wrow + k*WFS + dq*4);
        acc[k] += x.x*m.x; acc[k] += x.y*m.y; acc[k] += x.z*m.z; acc[k] += x.w*m.w;
      }
      m = mn;
    }
    #pragma unroll
    for (int k = 0; k < 16; ++k){
      float a = acc[k] * SCALE;
      float mx = wave_max64(a);
      float e = __expf(a - mx);
      float p = e / wave_sum64(e);
      aux_s[(r0 + k)*128 + lane] = p;
    }
  }
  // (no barrier: P2b reads only own-wave aux rows, writes own-wave wf rows)

  // P2b: wf += P @ v.   cols {lane, lane+64}.
  {
    const float4* v4 = (const float4*)vbp + (size_t)b*2048 + lane;  // + pq*128
    float a0[16], a1[16];
    #pragma unroll
    for (int k = 0; k < 16; ++k){ a0[k] = 0.f; a1[k] = 0.f; }
    float4 v0 = v4[0], v1 = v4[64];
    for (int pq = 0; pq < 16; ++pq){
      int nq = (pq + 1 < 16) ? pq + 1 : 15;
      float4 v0n = v4[nq*128], v1n = v4[nq*128 + 64];
      #pragma unroll
      for (int k = 0; k < 16; ++k){
        float4 p4 = *(const float4*)(aux_s + (r0 + k)*128 + pq*4);
        a0[k] += p4.x*v0.x; a0[k] += p4.y*v0.y; a0[k] += p4.z*v0.z; a0[k] += p4.w*v0.w;
        a1[k] += p4.x*v1.x; a1[k] += p4.y*v1.y; a1[k] += p4.z*v1.z; a1[k] += p4.w*v1.w;
      }
      v0 = v0n; v1 = v1n;
    }
    #pragma unroll
    for (int k = 0; k < 16; ++k){
      wf_s[(r0 + k)*WFS + lane]      += a0[k];
      wf_s[(r0 + k)*WFS + lane + 64] += a1[k];
    }
  }
  // (no barrier: P3 is row-local)

  // P3: MLP1  wf += gelu(wf @ l0w^T + l0b)
  {
    const float4* w4 = (const float4*)l0wp + lane;    // + dq*128 (+64)
    float bias0 = l0b[lane], bias1 = l0b[lane + 64];
    float a0[16], a1[16];
    #pragma unroll
    for (int k = 0; k < 16; ++k){ a0[k] = bias0; a1[k] = bias1; }
    float4 w0 = w4[0], w1 = w4[64];
    for (int dq = 0; dq < 32; ++dq){
      int nq = (dq + 1 < 32) ? dq + 1 : 31;
      float4 w0n = w4[nq*128], w1n = w4[nq*128 + 64];
      #pragma unroll
      for (int k = 0; k < 16; ++k){
        float4 x = *(const float4*)(wf_s + (r0 + k)*WFS + dq*4);
        a0[k] += x.x*w0.x; a0[k] += x.y*w0.y; a0[k] += x.z*w0.z; a0[k] += x.w*w0.w;
        a1[k] += x.x*w1.x; a1[k] += x.y*w1.y; a1[k] += x.z*w1.z; a1[k] += x.w*w1.w;
      }
      w0 = w0n; w1 = w1n;
    }
    // same-wave lockstep: all dq reads of own rows precede these writes
    #pragma unroll
    for (int k = 0; k < 16; ++k){
      wf_s[(r0 + k)*WFS + lane]      += gelu_f(a0[k]);
      wf_s[(r0 + k)*WFS + lane + 64] += gelu_f(a1[k]);
    }
  }

  // P4: T = wf @ M2 -> aux   (T[t,e] = sum_d wf[t,d] * M2T[e][d]); e = cols
  {
    const float4* w4 = (const float4*)m2p + lane;
    float a0[16], a1[16];
    #pragma unroll
    for (int k = 0; k < 16; ++k){ a0[k] = 0.f; a1[k] = 0.f; }
    float4 w0 = w4[0], w1 = w4[64];
    for (int dq = 0; dq < 32; ++dq){
      int nq = (dq + 1 < 32) ? dq + 1 : 31;
      float4 w0n = w4[nq*128], w1n = w4[nq*128 + 64];
      #pragma unroll
      for (int k = 0; k < 16; ++k){
        float4 x = *(const float4*)(wf_s + (r0 + k)*WFS + dq*4);
        a0[k] += x.x*w0.x; a0[k] += x.y*w0.y; a0[k] += x.z*w0.z; a0[k] += x.w*w0.w;
        a1[k] += x.x*w1.x; a1[k] += x.y*w1.y; a1[k] += x.z*w1.z; a1[k] += x.w*w1.w;
      }
      w0 = w0n; w1 = w1n;
    }
    #pragma unroll
    for (int k = 0; k < 16; ++k){
      aux_s[(r0 + k)*128 + lane]      = a0[k];
      aux_s[(r0 + k)*128 + lane + 64] = a1[k];
    }
  }
  __syncthreads();   // P5a reads wf across all rows (cross-wave)

  // P5a: S2[t,t'] = scale * sum_e T[t,e]*wf[t',e]; softmax; P -> aux[t][0..63]
  //      t = own rows, t' = lane.
  {
    float acc[16];
    #pragma unroll
    for (int k = 0; k < 16; ++k) acc[k] = 0.f;
    const float* trow = aux_s + r0*128;
    for (int eq = 0; eq < 32; ++eq){
      float4 wr = *(const float4*)(wf_s + lane*WFS + eq*4);   // per-lane row
      #pragma unroll
      for (int k = 0; k < 16; ++k){
        float4 t4 = *(const float4*)(trow + k*128 + eq*4);
        acc[k] += t4.x*wr.x; acc[k] += t4.y*wr.y; acc[k] += t4.z*wr.z; acc[k] += t4.w*wr.w;
      }
    }
    #pragma unroll
    for (int k = 0; k < 16; ++k){
      float a = acc[k] * SCALE;
      float mx = wave_max64(a);
      float e = __expf(a - mx);
      float p = e / wave_sum64(e);
      aux_s[(r0 + k)*128 + lane] = p;   // own rows; wave's T reads already done
    }
  }
  // (no barrier: P5b reads own aux rows + wf (unchanged since last barrier))

  // P5b: U = P @ wf  -> overwrites aux own rows.
  {
    float a0[16], a1[16];
    #pragma unroll
    for (int k = 0; k < 16; ++k){ a0[k] = 0.f; a1[k] = 0.f; }
    for (int tq = 0; tq < 16; ++tq){
      float w00 = wf_s[(4*tq + 0)*WFS + lane];
      float w01 = wf_s[(4*tq + 1)*WFS + lane];
      float w02 = wf_s[(4*tq + 2)*WFS + lane];
      float w03 = wf_s[(4*tq + 3)*WFS + lane];
      float w10 = wf_s[(4*tq + 0)*WFS + lane + 64];
      float w11 = wf_s[(4*tq + 1)*WFS + lane + 64];
      float w12 = wf_s[(4*tq + 2)*WFS + lane + 64];
      float w13 = wf_s[(4*tq + 3)*WFS + lane + 64];
      #pragma unroll
      for (int k = 0; k < 16; ++k){
        float4 p4 = *(const float4*)(aux_s + (r0 + k)*128 + tq*4);
        a0[k] += p4.x*w00; a0[k] += p4.y*w01; a0[k] += p4.z*w02; a0[k] += p4.w*w03;
        a1[k] += p4.x*w10; a1[k] += p4.y*w11; a1[k] += p4.z*w12; a1[k] += p4.w*w13;
      }
    }
    // own-row overwrite after own-row reads (lockstep)
    #pragma unroll
    for (int k = 0; k < 16; ++k){
      aux_s[(r0 + k)*128 + lane]      = a0[k];
      aux_s[(r0 + k)*128 + lane + 64] = a1[k];
    }
  }
  // (no barrier before P6 GEMM: it reads only own aux rows)

  // P6: av2 = U @ Wv2^T with the swapaxes reshape quirk:
  //     target of (q, cp) is wf[cp>>1][(cp&1)*64 + q];  cp = lane, lane+64.
  {
    const float4* w4 = (const float4*)wv2p + lane;
    float a0[16], a1[16];
    #pragma unroll
    for (int k = 0; k < 16; ++k){ a0[k] = 0.f; a1[k] = 0.f; }
    float4 w0 = w4[0], w1 = w4[64];
    for (int dq = 0; dq < 32; ++dq){
      int nq = (dq + 1 < 32) ? dq + 1 : 31;
      float4 w0n = w4[nq*128], w1n = w4[nq*128 + 64];
      #pragma unroll
      for (int k = 0; k < 16; ++k){
        float4 u4 = *(const float4*)(aux_s + (r0 + k)*128 + dq*4);
        a0[k] += u4.x*w0.x; a0[k] += u4.y*w0.y; a0[k] += u4.z*w0.z; a0[k] += u4.w*w0.w;
        a1[k] += u4.x*w1.x; a1[k] += u4.y*w1.y; a1[k] += u4.z*w1.z; a1[k] += u4.w*w1.w;
      }
      w0 = w0n; w1 = w1n;
    }
    __syncthreads();   // all cross-wave wf reads (P5a/P5b) complete before scatter
    int rr = lane >> 1, cb = (lane & 1)*64;
    #pragma unroll
    for (int k = 0; k < 16; ++k){
      int q = r0 + k;
      wf_s[rr*WFS + cb + q]        += a0[k];   // cp = lane
      wf_s[(32 + rr)*WFS + cb + q] += a1[k];   // cp = lane+64 (bijective, no race)
    }
  }
  __syncthreads();   // P7 reads rows written by other waves' scatters

  // P7: MLP2  wf += gelu(wf @ pw^T + pb)   (row-local)
  {
    const float4* w4 = (const float4*)pwp + lane;
    float bias0 = pb[lane], bias1 = pb[lane + 64];
    float a0[16], a1[16];
    #pragma unroll
    for (int k = 0; k < 16; ++k){ a0[k] = bias0; a1[k] = bias1; }
    float4 w0 = w4[0], w1 = w4[64];
    for (int dq = 0; dq < 32; ++dq){
      int nq = (dq + 1 < 32) ? dq + 1 : 31;
      float4 w0n = w4[nq*128], w1n = w4[nq*128 + 64];
      #pragma unroll
      for (int k = 0; k < 16; ++k){
        float4 x = *(const float4*)(wf_s + (r0 + k)*WFS + dq*4);
        a0[k] += x.x*w0.x; a0[k] += x.y*w0.y; a0[k] += x.z*w0.z; a0[k] += x.w*w0.w;
        a1[k] += x.x*w1.x; a1[k] += x.y*w1.y; a1[k] += x.z*w1.z; a1[k] += x.w*w1.w;
      }
      w0 = w0n; w1 = w1n;
    }
    #pragma unroll
    for (int k = 0; k < 16; ++k){
      wf_s[(r0 + k)*WFS + lane]      += gelu_f(a0[k]);
      wf_s[(r0 + k)*WFS + lane + 64] += gelu_f(a1[k]);
    }
  }
  __syncthreads();   // P8 reads wf cross-wave

  // P8: scatter back into out (pass-through copy already done by pool_k)
  {
    float* outb = out + ((size_t)b*128)*512*512;
    #pragma unroll
    for (int it = 0; it < 8; ++it){
      int idx = it*256 + tid;
      int c = idx >> 4, rem = idx & 15, r = rem >> 1, q = rem & 1;
      int t0 = r*8 + q*4;
      float4 v;
      v.x = wf_s[(t0+0)*WFS + c];
      v.y = wf_s[(t0+1)*WFS + c];
      v.z = wf_s[(t0+2)*WFS + c];
      v.w = wf_s[(t0+3)*WFS + c];
      *(float4*)(outb + ((size_t)c*512 + ih*8 + r)*512 + iw*8 + q*4) = v;
    }
  }
}

extern "C" void kernel_launch(void* const* d_in, const int* in_sizes, int n_in,
                              void* d_out, int out_size, void* d_ws, size_t ws_size,
                              hipStream_t stream) {
  const float* fm   = (const float*)d_in[0];
  const float* unc  = (const float*)d_in[1];
  const float* qgw  = (const float*)d_in[2];
  const float* kvw  = (const float*)d_in[3];
  const float* l0w  = (const float*)d_in[4];
  const float* l0b  = (const float*)d_in[5];
  const float* qkvw = (const float*)d_in[6];
  const float* pw   = (const float*)d_in[7];
  const float* pb   = (const float*)d_in[8];
  float* out = (float*)d_out;

  // Workspace layout with live-range aliasing (total 110592 floats = 432 KB)
  float* ws     = (float*)d_ws;
  float* scores = ws;                      // 8192
  int*   sel    = (int*)(ws + 8192);       // 2456 (padded to 4096)
  float* g      = ws + 12288;              // 16384
  float* mbp    = ws + 12288;              // aliases g (g dead after kv_k)
  float* kbuf   = ws + 28672;              // 16384
  float* wv2p   = ws + 28672;              // aliases kbuf (dead after mb_k)
  float* vbp    = ws + 45056;              // 16384 (packed p-quads)
  float* m2p    = ws + 61440;              // 16384 (packed d-quads)
  float* l0wp   = ws + 77824;              // 16384
  float* pwp    = ws + 94208;              // 16384

  score_k <<<B_*NWIN, 64, 0, stream>>>(unc, scores);
  select_k<<<B_, 1024, 0, stream>>>(scores, sel);
  pool_k  <<<B_*C_*64, 256, 0, stream>>>(fm, g, out);   // fused out=fm copy
  kv_k    <<<64, 256, 0, stream>>>(g, kvw, kbuf, vbp);
  mb_k    <<<64, 256, 0, stream>>>(kbuf, qgw, mbp);
  m2p_k   <<<16, 256, 0, stream>>>(qkvw, m2p);
  pack_k  <<<16, 256, 0, stream>>>(l0w, pw, qkvw, l0wp, pwp, wv2p);
  mega_k  <<<NSEL, 256, 0, stream>>>(fm, sel, mbp, vbp, m2p, wv2p,
                                     l0wp, l0b, pwp, pb, out);
}